// Round 3
// baseline (1159.192 us; speedup 1.0000x reference)
//
#include <hip/hip_runtime.h>

#define N_NODES 50000
#define E_EDGES 800000
#define D_OUT   64
#define COMB    144   // 64 + 64 + 16
#define GRID_E  1024  // persistent edge-kernel blocks (must match launch)

typedef float  f32x4  __attribute__((ext_vector_type(4)));
typedef __bf16 bf16x8 __attribute__((ext_vector_type(8)));
typedef __bf16 bf16x4 __attribute__((ext_vector_type(4)));

// workspace layout (bytes):
//   [0, 12.8MB)            num  : N*64 f32 atomics
//   [12.8MB, 14.4MB)       den  : N*8  f32 atomics
//   [14.4MB, +107.5KB)     bf16 transposed+padded weights
#define WS_NUM_OFF   0
#define WS_DEN_OFF   (12800000)
#define WS_WTS_OFF   (14400000)
#define BIG_ELEMS    (64*168)   // 10752
#define SMALL_ELEMS  (64*72)    // 4608

// ---------------------------------------------------------------------------
// prep: convert fp32 [K][64] weights to bf16 transposed [64][Kpad] (zero pad)
// ---------------------------------------------------------------------------
__global__ __launch_bounds__(256) void prep_kernel(
    const float* __restrict__ kW0, const float* __restrict__ kW1, const float* __restrict__ kW2,
    const float* __restrict__ vW0, const float* __restrict__ vW1, const float* __restrict__ vW2,
    const float* __restrict__ oW0, const float* __restrict__ oW1, const float* __restrict__ oW2,
    __bf16* __restrict__ wout)
{
    const int b = blockIdx.x, tid = threadIdx.x;
    const float* src;
    __bf16* dst;
    int K, Kpad, lb;
    if (b < 42)      { src = kW0; dst = wout;             K = 144; Kpad = 168; lb = b; }
    else if (b < 84) { src = vW0; dst = wout + BIG_ELEMS; K = 144; Kpad = 168; lb = b - 42; }
    else {
        const int id = (b - 84) / 18; lb = (b - 84) % 18;
        const float* s7[7] = {kW1, kW2, vW1, vW2, oW0, oW1, oW2};
        src = s7[id]; dst = wout + 2 * BIG_ELEMS + id * SMALL_ELEMS;
        K = 64; Kpad = 72;
    }
    const int idx = lb * 256 + tid;
    const int col = idx / Kpad, k = idx % Kpad;
    dst[idx] = (k < K) ? (__bf16)src[k * 64 + col] : (__bf16)0.f;
}

// ---------------------------------------------------------------------------
// MFMA fragment convention (both operands use the SAME contiguous k = hi*8+i
// placement, so any HW k-permutation cancels):
//   A: lane holds A[row=lane&15][k=(lane>>4)*8+i]
//   B: lane holds B[k=(lane>>4)*8+i][col=lane&15]  <- from Wt[col][k]
//   D: d[r] = D[row=(lane>>4)*4+r][col=lane&15]
// ---------------------------------------------------------------------------
__device__ __forceinline__ void gemm64(const __bf16* Arow, const __bf16* Wt,
                                       int hi, int row16, f32x4 acc[4])
{
    #pragma unroll
    for (int kc = 0; kc < 2; ++kc) {
        const bf16x8 a = *(const bf16x8*)(Arow + kc * 32 + hi * 8);
        #pragma unroll
        for (int n = 0; n < 4; ++n) {
            const bf16x8 bfr = *(const bf16x8*)(Wt + (n * 16 + row16) * 72 + kc * 32 + hi * 8);
            acc[n] = __builtin_amdgcn_mfma_f32_16x16x32_bf16(a, bfr, acc[n], 0, 0, 0);
        }
    }
}

// ---------------------------------------------------------------------------
// Edge kernel: persistent blocks, grid-stride over 64-edge tiles.
// Pipeline: at tile-top issue next tile's x-gather (regs) + t+2 idx load;
// they complete under the current tile's two MLP stacks.
// ---------------------------------------------------------------------------
__global__ __launch_bounds__(256, 4) void edge_kernel(
    const float* __restrict__ x,
    const float* __restrict__ edge_attr,
    const int*   __restrict__ edge_index,
    const float* __restrict__ q,
    const float* __restrict__ kb0, const float* __restrict__ kb1, const float* __restrict__ kb2,
    const float* __restrict__ vb0, const float* __restrict__ vb1, const float* __restrict__ vb2,
    const __bf16* __restrict__ kW0t, const __bf16* __restrict__ kW1t, const __bf16* __restrict__ kW2t,
    const __bf16* __restrict__ vW0t, const __bf16* __restrict__ vW1t, const __bf16* __restrict__ vW2t,
    float* __restrict__ num, float* __restrict__ den)
{
    __shared__ __bf16 feat_s[64][168];   // [edge][k], k 144..167 zero (set once)
    __shared__ __bf16 H_s[64][72];       // per-wave-private 16-row stripes
    __shared__ int    idx_s[2][128];     // [buf][0..63 src | 64..127 dst]

    const int tid   = threadIdx.x;
    const int lane  = tid & 63;
    const int w     = tid >> 6;
    const int row16 = lane & 15;
    const int hi    = lane >> 4;
    const int wrow  = w * 16;

    // gather mapping: thread covers rows rb, rb+8, ..., rb+56 at one 16B column
    const int jj  = tid & 31;            // 0..15 -> src cols, 16..31 -> dst cols
    const int rb  = tid >> 5;            // 0..7
    const int sel = (jj < 16) ? 0 : 64;  // idx_s offset AND feat col offset
    const int c4  = (jj & 15) * 4;

    const int nt = E_EDGES / 64;         // 12500

    // zero feat pad cols 144..167 (never rewritten)
    for (int i = tid; i < 64 * 6; i += 256) {
        bf16x4 z; z[0] = z[1] = z[2] = z[3] = (__bf16)0.f;
        *(bf16x4*)&feat_s[i / 6][144 + (i % 6) * 4] = z;
    }

    float qv4[4];
    #pragma unroll
    for (int n = 0; n < 4; ++n) qv4[n] = q[n * 16 + row16];

    // ---------------- prologue: tile t0 ----------------
    int t = blockIdx.x;
    if (tid < 128)
        idx_s[0][tid] = edge_index[(tid >= 64 ? E_EDGES + t * 64 + tid - 64
                                              : t * 64 + tid)];
    __syncthreads();
    {
        float4 g[8];
        #pragma unroll
        for (int k = 0; k < 8; ++k) {
            const int node = idx_s[0][sel + rb + k * 8];
            g[k] = *(const float4*)&x[(size_t)node * 64 + c4];
        }
        const float4 ea4 = *(const float4*)&edge_attr[((size_t)t * 64 + (tid >> 2)) * 16 + (tid & 3) * 4];
        #pragma unroll
        for (int k = 0; k < 8; ++k) {
            bf16x4 h; h[0] = (__bf16)g[k].x; h[1] = (__bf16)g[k].y;
                      h[2] = (__bf16)g[k].z; h[3] = (__bf16)g[k].w;
            *(bf16x4*)&feat_s[rb + k * 8][sel + c4] = h;
        }
        bf16x4 he; he[0] = (__bf16)ea4.x; he[1] = (__bf16)ea4.y;
                   he[2] = (__bf16)ea4.z; he[3] = (__bf16)ea4.w;
        *(bf16x4*)&feat_s[tid >> 2][128 + (tid & 3) * 4] = he;

        if (t + GRID_E < nt && tid < 128)
            idx_s[1][tid] = edge_index[(tid >= 64 ? E_EDGES + (t + GRID_E) * 64 + tid - 64
                                                  : (t + GRID_E) * 64 + tid)];
    }
    __syncthreads();

    int bufA = 0;   // idx_s[bufA] = current tile, idx_s[bufA^1] = next tile

    // ---------------- main loop ----------------
    for (; t < nt; t += GRID_E) {
        const int  B    = bufA ^ 1;
        const bool pre  = (t + GRID_E)     < nt;
        const bool pre2 = (t + 2 * GRID_E) < nt;

        // --- issue next tile's gather + t+2 idx load (latency hidden below) ---
        float4 g[8]; float4 ea4;
        if (pre) {
            #pragma unroll
            for (int k = 0; k < 8; ++k) {
                const int node = idx_s[B][sel + rb + k * 8];
                g[k] = *(const float4*)&x[(size_t)node * 64 + c4];
            }
            ea4 = *(const float4*)&edge_attr[((size_t)(t + GRID_E) * 64 + (tid >> 2)) * 16 + (tid & 3) * 4];
        }
        int inext = 0;
        if (pre2 && tid < 128)
            inext = edge_index[(tid >= 64 ? E_EDGES + (t + 2 * GRID_E) * 64 + tid - 64
                                          : (t + 2 * GRID_E) * 64 + tid)];

        const __bf16* frow = &feat_s[wrow + row16][0];
        const __bf16* hrow = &H_s[wrow + row16][0];

        float kk[4][4], vv[4][4];
        float h0V[4][4];   // V-stack h0, carried across barrier

        // ================= K stack =================
        {
            f32x4 acc[4] = {{0,0,0,0},{0,0,0,0},{0,0,0,0},{0,0,0,0}};
            #pragma unroll
            for (int kc = 0; kc < 5; ++kc) {
                const bf16x8 a = *(const bf16x8*)(frow + kc * 32 + hi * 8);
                #pragma unroll
                for (int n = 0; n < 4; ++n) {
                    const bf16x8 bfr = *(const bf16x8*)(kW0t + (n * 16 + row16) * 168 + kc * 32 + hi * 8);
                    acc[n] = __builtin_amdgcn_mfma_f32_16x16x32_bf16(a, bfr, acc[n], 0, 0, 0);
                }
            }
            float h0[4][4];
            #pragma unroll
            for (int n = 0; n < 4; ++n) {
                const float bias = kb0[n * 16 + row16];
                #pragma unroll
                for (int r = 0; r < 4; ++r) {
                    h0[n][r] = fmaxf(acc[n][r] + bias, 0.f);
                    H_s[wrow + hi * 4 + r][n * 16 + row16] = (__bf16)h0[n][r];
                }
            }
            f32x4 acc1[4] = {{0,0,0,0},{0,0,0,0},{0,0,0,0},{0,0,0,0}};
            gemm64(hrow, kW1t, hi, row16, acc1);
            float h1[4][4];
            #pragma unroll
            for (int n = 0; n < 4; ++n) {
                const float bias = kb1[n * 16 + row16];
                #pragma unroll
                for (int r = 0; r < 4; ++r) {
                    h1[n][r] = fmaxf(h0[n][r] + acc1[n][r] + bias, 0.f);
                    H_s[wrow + hi * 4 + r][n * 16 + row16] = (__bf16)h1[n][r];
                }
            }
            f32x4 acc2[4] = {{0,0,0,0},{0,0,0,0},{0,0,0,0},{0,0,0,0}};
            gemm64(hrow, kW2t, hi, row16, acc2);
            #pragma unroll
            for (int n = 0; n < 4; ++n) {
                const float bias = kb2[n * 16 + row16];
                #pragma unroll
                for (int r = 0; r < 4; ++r)
                    kk[n][r] = h1[n][r] + acc2[n][r] + bias;
            }
        }

        // --- attention scores (head = 2n + (row16>>3)) ---
        float ex[4][4];
        #pragma unroll
        for (int n = 0; n < 4; ++n)
            #pragma unroll
            for (int r = 0; r < 4; ++r) {
                float p = qv4[n] * kk[n][r];
                p += __shfl_xor(p, 1);
                p += __shfl_xor(p, 2);
                p += __shfl_xor(p, 4);
                ex[n][r] = __expf(p * 0.35355339059327373f); // shift-free softmax: scores O(1)
            }

        // dst for this tile (read before idx_s[bufA] is overwritten after B1)
        int dst4[4];
        #pragma unroll
        for (int r = 0; r < 4; ++r) dst4[r] = idx_s[bufA][64 + wrow + hi * 4 + r];

        // ================= V stack: L0 (last feat_s reader) =================
        {
            f32x4 acc[4] = {{0,0,0,0},{0,0,0,0},{0,0,0,0},{0,0,0,0}};
            #pragma unroll
            for (int kc = 0; kc < 5; ++kc) {
                const bf16x8 a = *(const bf16x8*)(frow + kc * 32 + hi * 8);
                #pragma unroll
                for (int n = 0; n < 4; ++n) {
                    const bf16x8 bfr = *(const bf16x8*)(vW0t + (n * 16 + row16) * 168 + kc * 32 + hi * 8);
                    acc[n] = __builtin_amdgcn_mfma_f32_16x16x32_bf16(a, bfr, acc[n], 0, 0, 0);
                }
            }
            #pragma unroll
            for (int n = 0; n < 4; ++n) {
                const float bias = vb0[n * 16 + row16];
                #pragma unroll
                for (int r = 0; r < 4; ++r) {
                    h0V[n][r] = fmaxf(acc[n][r] + bias, 0.f);
                    H_s[wrow + hi * 4 + r][n * 16 + row16] = (__bf16)h0V[n][r];
                }
            }
        }

        __syncthreads();   // B1: all feat_s / idx_s reads for tile t complete

        if (pre2 && tid < 128) idx_s[bufA][tid] = inext;  // bufA becomes t+2 buffer

        // ================= V stack: L1, L2 =================
        {
            f32x4 acc1[4] = {{0,0,0,0},{0,0,0,0},{0,0,0,0},{0,0,0,0}};
            gemm64(hrow, vW1t, hi, row16, acc1);
            float h1[4][4];
            #pragma unroll
            for (int n = 0; n < 4; ++n) {
                const float bias = vb1[n * 16 + row16];
                #pragma unroll
                for (int r = 0; r < 4; ++r) {
                    h1[n][r] = fmaxf(h0V[n][r] + acc1[n][r] + bias, 0.f);
                    H_s[wrow + hi * 4 + r][n * 16 + row16] = (__bf16)h1[n][r];
                }
            }
            f32x4 acc2[4] = {{0,0,0,0},{0,0,0,0},{0,0,0,0},{0,0,0,0}};
            gemm64(hrow, vW2t, hi, row16, acc2);
            #pragma unroll
            for (int n = 0; n < 4; ++n) {
                const float bias = vb2[n * 16 + row16];
                #pragma unroll
                for (int r = 0; r < 4; ++r)
                    vv[n][r] = h1[n][r] + acc2[n][r] + bias;
            }
        }

        // --- atomic scatter ---
        const int b3 = row16 >> 3;
        #pragma unroll
        for (int r = 0; r < 4; ++r) {
            const int drow = dst4[r];
            if ((lane & 7) == 0) {
                #pragma unroll
                for (int n = 0; n < 4; ++n)
                    atomicAdd(&den[(size_t)drow * 8 + 2 * n + b3], ex[n][r]);
            }
            #pragma unroll
            for (int n = 0; n < 4; ++n)
                atomicAdd(&num[(size_t)drow * 64 + n * 16 + row16], ex[n][r] * vv[n][r]);
        }

        // --- store prefetched next tile into feat_s ---
        if (pre) {
            #pragma unroll
            for (int k = 0; k < 8; ++k) {
                bf16x4 h; h[0] = (__bf16)g[k].x; h[1] = (__bf16)g[k].y;
                          h[2] = (__bf16)g[k].z; h[3] = (__bf16)g[k].w;
                *(bf16x4*)&feat_s[rb + k * 8][sel + c4] = h;
            }
            bf16x4 he; he[0] = (__bf16)ea4.x; he[1] = (__bf16)ea4.y;
                       he[2] = (__bf16)ea4.z; he[3] = (__bf16)ea4.w;
            *(bf16x4*)&feat_s[tid >> 2][128 + (tid & 3) * 4] = he;
        }

        __syncthreads();   // B2: feat(t+1) + idx(t+2) visible
        bufA ^= 1;
    }
}

// ---------------------------------------------------------------------------
// Node kernel: block = 64 nodes; aggr = relu(num/den) -> out stack -> skip.
// ---------------------------------------------------------------------------
__global__ __launch_bounds__(256) void node_kernel(
    const float* __restrict__ x,
    const float* __restrict__ num, const float* __restrict__ den,
    const float* __restrict__ ob0, const float* __restrict__ ob1, const float* __restrict__ ob2,
    const __bf16* __restrict__ oW0t, const __bf16* __restrict__ oW1t, const __bf16* __restrict__ oW2t,
    float* __restrict__ out)
{
    __shared__ __bf16 A_s[64][72];
    __shared__ __bf16 H_s[64][72];

    const int tid  = threadIdx.x;
    const int lane = tid & 63;
    const int w    = tid >> 6;
    const int n0   = blockIdx.x * 64;
    const int row16 = lane & 15;
    const int hi    = lane >> 4;

    for (int i = tid; i < 64 * 16; i += 256) {
        const int r = i >> 4, cc = (i & 15) * 4;
        const int node = n0 + r;
        bf16x4 h; h[0] = h[1] = h[2] = h[3] = (__bf16)0.f;
        if (node < N_NODES) {
            const float dh = den[(size_t)node * 8 + (cc >> 3)];
            if (dh > 0.f) {
                const float4 f = *(const float4*)&num[(size_t)node * 64 + cc];
                const float inv = 1.f / dh;
                h[0] = (__bf16)fmaxf(f.x * inv, 0.f);
                h[1] = (__bf16)fmaxf(f.y * inv, 0.f);
                h[2] = (__bf16)fmaxf(f.z * inv, 0.f);
                h[3] = (__bf16)fmaxf(f.w * inv, 0.f);
            }
        }
        *(bf16x4*)&A_s[r][cc] = h;
    }
    __syncthreads();

    const __bf16* arow = &A_s[w * 16 + row16][0];
    const __bf16* hrow = &H_s[w * 16 + row16][0];

    f32x4 acc[4] = {{0,0,0,0},{0,0,0,0},{0,0,0,0},{0,0,0,0}};
    gemm64(arow, oW0t, hi, row16, acc);
    float h0[4][4];
    #pragma unroll
    for (int n = 0; n < 4; ++n) {
        const float bias = ob0[n * 16 + row16];
        #pragma unroll
        for (int r = 0; r < 4; ++r) {
            h0[n][r] = fmaxf(acc[n][r] + bias, 0.f);
            H_s[w * 16 + hi * 4 + r][n * 16 + row16] = (__bf16)h0[n][r];
        }
    }

    f32x4 acc1[4] = {{0,0,0,0},{0,0,0,0},{0,0,0,0},{0,0,0,0}};
    gemm64(hrow, oW1t, hi, row16, acc1);
    float h1[4][4];
    #pragma unroll
    for (int n = 0; n < 4; ++n) {
        const float bias = ob1[n * 16 + row16];
        #pragma unroll
        for (int r = 0; r < 4; ++r) {
            h1[n][r] = fmaxf(h0[n][r] + acc1[n][r] + bias, 0.f);
            H_s[w * 16 + hi * 4 + r][n * 16 + row16] = (__bf16)h1[n][r];
        }
    }

    f32x4 acc2[4] = {{0,0,0,0},{0,0,0,0},{0,0,0,0},{0,0,0,0}};
    gemm64(hrow, oW2t, hi, row16, acc2);
    #pragma unroll
    for (int n = 0; n < 4; ++n) {
        const float bias = ob2[n * 16 + row16];
        #pragma unroll
        for (int r = 0; r < 4; ++r) {
            const int node = n0 + w * 16 + hi * 4 + r;
            if (node < N_NODES) {
                const int col = n * 16 + row16;
                const float o = h1[n][r] + acc2[n][r] + bias;
                out[(size_t)node * 64 + col] = fmaxf(x[(size_t)node * 64 + col] + o, 0.f);
            }
        }
    }
}

extern "C" void kernel_launch(void* const* d_in, const int* in_sizes, int n_in,
                              void* d_out, int out_size, void* d_ws, size_t ws_size,
                              hipStream_t stream) {
    const float* x  = (const float*)d_in[0];
    const float* ea = (const float*)d_in[1];
    const int*   ei = (const int*)d_in[2];
    const float* q  = (const float*)d_in[3];
    const float* kW0 = (const float*)d_in[4];  const float* kb0 = (const float*)d_in[5];
    const float* kW1 = (const float*)d_in[6];  const float* kb1 = (const float*)d_in[7];
    const float* kW2 = (const float*)d_in[8];  const float* kb2 = (const float*)d_in[9];
    const float* vW0 = (const float*)d_in[10]; const float* vb0 = (const float*)d_in[11];
    const float* vW1 = (const float*)d_in[12]; const float* vb1 = (const float*)d_in[13];
    const float* vW2 = (const float*)d_in[14]; const float* vb2 = (const float*)d_in[15];
    const float* oW0 = (const float*)d_in[16]; const float* ob0 = (const float*)d_in[17];
    const float* oW1 = (const float*)d_in[18]; const float* ob1 = (const float*)d_in[19];
    const float* oW2 = (const float*)d_in[20]; const float* ob2 = (const float*)d_in[21];

    char* ws = (char*)d_ws;
    float*  num  = (float*)(ws + WS_NUM_OFF);
    float*  den  = (float*)(ws + WS_DEN_OFF);
    __bf16* wts  = (__bf16*)(ws + WS_WTS_OFF);
    __bf16* kW0t = wts;
    __bf16* vW0t = wts + BIG_ELEMS;
    __bf16* sm   = wts + 2 * BIG_ELEMS;
    __bf16* kW1t = sm;                   __bf16* kW2t = sm + SMALL_ELEMS;
    __bf16* vW1t = sm + 2 * SMALL_ELEMS; __bf16* vW2t = sm + 3 * SMALL_ELEMS;
    __bf16* oW0t = sm + 4 * SMALL_ELEMS; __bf16* oW1t = sm + 5 * SMALL_ELEMS;
    __bf16* oW2t = sm + 6 * SMALL_ELEMS;

    hipMemsetAsync(d_ws, 0, (size_t)N_NODES * (64 + 8) * sizeof(float), stream);

    prep_kernel<<<210, 256, 0, stream>>>(kW0, kW1, kW2, vW0, vW1, vW2, oW0, oW1, oW2, wts);

    edge_kernel<<<GRID_E, 256, 0, stream>>>(
        x, ea, ei, q,
        kb0, kb1, kb2, vb0, vb1, vb2,
        kW0t, kW1t, kW2t, vW0t, vW1t, vW2t,
        num, den);

    node_kernel<<<(N_NODES + 63) / 64, 256, 0, stream>>>(
        x, num, den, ob0, ob1, ob2, oW0t, oW1t, oW2t, (float*)d_out);
}

// Round 4
// 453.196 us; speedup vs baseline: 2.5578x; 2.5578x over previous
//
#include <hip/hip_runtime.h>

#define N_NODES 50000
#define E_EDGES 800000
#define D_OUT   64
#define COMB    144   // 64 + 64 + 16

typedef float  f32x4  __attribute__((ext_vector_type(4)));
typedef __bf16 bf16x8 __attribute__((ext_vector_type(8)));
typedef __bf16 bf16x4 __attribute__((ext_vector_type(4)));

// workspace layout (bytes):
//   [0, 12.8MB)            num  : N*64 f32 atomics
//   [12.8MB, 14.4MB)       den  : N*8  f32 atomics
//   [14.4MB, +107.5KB)     bf16 transposed+padded weights
#define WS_NUM_OFF   0
#define WS_DEN_OFF   (12800000)
#define WS_WTS_OFF   (14400000)
#define BIG_ELEMS    (64*168)   // 10752
#define SMALL_ELEMS  (64*72)    // 4608

// ---------------------------------------------------------------------------
// prep: convert fp32 [K][64] weights to bf16 transposed [64][Kpad] (zero pad)
// ---------------------------------------------------------------------------
__global__ __launch_bounds__(256) void prep_kernel(
    const float* __restrict__ kW0, const float* __restrict__ kW1, const float* __restrict__ kW2,
    const float* __restrict__ vW0, const float* __restrict__ vW1, const float* __restrict__ vW2,
    const float* __restrict__ oW0, const float* __restrict__ oW1, const float* __restrict__ oW2,
    __bf16* __restrict__ wout)
{
    const int b = blockIdx.x, tid = threadIdx.x;
    const float* src;
    __bf16* dst;
    int K, Kpad, lb;
    if (b < 42)      { src = kW0; dst = wout;             K = 144; Kpad = 168; lb = b; }
    else if (b < 84) { src = vW0; dst = wout + BIG_ELEMS; K = 144; Kpad = 168; lb = b - 42; }
    else {
        const int id = (b - 84) / 18; lb = (b - 84) % 18;
        const float* s7[7] = {kW1, kW2, vW1, vW2, oW0, oW1, oW2};
        src = s7[id]; dst = wout + 2 * BIG_ELEMS + id * SMALL_ELEMS;
        K = 64; Kpad = 72;
    }
    const int idx = lb * 256 + tid;
    const int col = idx / Kpad, k = idx % Kpad;
    dst[idx] = (k < K) ? (__bf16)src[k * 64 + col] : (__bf16)0.f;
}

// ---------------------------------------------------------------------------
// MFMA fragment convention (both operands use the SAME contiguous k = hi*8+i
// placement, so any HW k-permutation cancels):
//   A: lane holds A[row=lane&15][k=(lane>>4)*8+i]
//   B: lane holds B[k=(lane>>4)*8+i][col=lane&15]  <- from Wt[col][k]
//   D: d[r] = D[row=(lane>>4)*4+r][col=lane&15]
// ---------------------------------------------------------------------------
__device__ __forceinline__ void gemm64(const __bf16* Arow, const __bf16* Wt,
                                       int hi, int row16, f32x4 acc[4])
{
    #pragma unroll
    for (int kc = 0; kc < 2; ++kc) {
        const bf16x8 a = *(const bf16x8*)(Arow + kc * 32 + hi * 8);
        #pragma unroll
        for (int n = 0; n < 4; ++n) {
            const bf16x8 bfr = *(const bf16x8*)(Wt + (n * 16 + row16) * 72 + kc * 32 + hi * 8);
            acc[n] = __builtin_amdgcn_mfma_f32_16x16x32_bf16(a, bfr, acc[n], 0, 0, 0);
        }
    }
}

__device__ __forceinline__ bf16x8 pack8(float4 a, float4 b) {
    bf16x8 r;
    r[0] = (__bf16)a.x; r[1] = (__bf16)a.y; r[2] = (__bf16)a.z; r[3] = (__bf16)a.w;
    r[4] = (__bf16)b.x; r[5] = (__bf16)b.y; r[6] = (__bf16)b.z; r[7] = (__bf16)b.w;
    return r;
}

// ---------------------------------------------------------------------------
// Edge kernel: one wave per 16 edges, fully independent waves, ZERO barriers.
// A-fragments gathered straight from global into registers (no feat LDS),
// loaded once, reused by both K and V stacks. H_s is per-wave-private.
// ---------------------------------------------------------------------------
__global__ __launch_bounds__(256, 6) void edge_kernel(
    const float* __restrict__ x,
    const float* __restrict__ edge_attr,
    const int*   __restrict__ edge_index,
    const float* __restrict__ q,
    const float* __restrict__ kb0, const float* __restrict__ kb1, const float* __restrict__ kb2,
    const float* __restrict__ vb0, const float* __restrict__ vb1, const float* __restrict__ vb2,
    const __bf16* __restrict__ kW0t, const __bf16* __restrict__ kW1t, const __bf16* __restrict__ kW2t,
    const __bf16* __restrict__ vW0t, const __bf16* __restrict__ vW1t, const __bf16* __restrict__ vW2t,
    float* __restrict__ num, float* __restrict__ den)
{
    __shared__ __bf16 H_s[64][72];        // wave w uses rows w*16 .. w*16+15 only

    const int tid   = threadIdx.x;
    const int lane  = tid & 63;
    const int w     = tid >> 6;
    const int row16 = lane & 15;
    const int hi    = lane >> 4;
    const int wrow  = w * 16;

    const int e0 = (blockIdx.x * 4 + w) * 16;   // wave's 16 edges
    const int er = e0 + row16;                  // this lane's A-row edge

    const int src  = edge_index[er];
    const int dstn = edge_index[E_EDGES + er];  // feat source AND scatter target

    // ---- L0 A-fragments: direct register gather (k = kc*32 + hi*8 + i) ----
    bf16x8 af[5];
    {
        const float* xs = &x[(size_t)src * 64 + hi * 8];
        af[0] = pack8(*(const float4*)xs,        *(const float4*)(xs + 4));
        af[1] = pack8(*(const float4*)(xs + 32), *(const float4*)(xs + 36));
        const float* xd = &x[(size_t)dstn * 64 + hi * 8];
        af[2] = pack8(*(const float4*)xd,        *(const float4*)(xd + 4));
        af[3] = pack8(*(const float4*)(xd + 32), *(const float4*)(xd + 36));
        if (hi < 2) {
            const float* ep = &edge_attr[(size_t)er * 16 + hi * 8];
            af[4] = pack8(*(const float4*)ep, *(const float4*)(ep + 4));
        } else {
            #pragma unroll
            for (int i = 0; i < 8; ++i) af[4][i] = (__bf16)0.f;
        }
    }

    const __bf16* hrow = &H_s[wrow + row16][0];
    float ex[4][4];

    // ================= K stack =================
    {
        f32x4 acc[4] = {{0,0,0,0},{0,0,0,0},{0,0,0,0},{0,0,0,0}};
        #pragma unroll
        for (int kc = 0; kc < 5; ++kc) {
            #pragma unroll
            for (int n = 0; n < 4; ++n) {
                const bf16x8 bfr = *(const bf16x8*)(kW0t + (n * 16 + row16) * 168 + kc * 32 + hi * 8);
                acc[n] = __builtin_amdgcn_mfma_f32_16x16x32_bf16(af[kc], bfr, acc[n], 0, 0, 0);
            }
        }
        float h0[4][4];
        #pragma unroll
        for (int n = 0; n < 4; ++n) {
            const float bias = kb0[n * 16 + row16];
            #pragma unroll
            for (int r = 0; r < 4; ++r) {
                h0[n][r] = fmaxf(acc[n][r] + bias, 0.f);
                H_s[wrow + hi * 4 + r][n * 16 + row16] = (__bf16)h0[n][r];
            }
        }
        __builtin_amdgcn_wave_barrier();          // order LDS write -> read (intra-wave)

        f32x4 acc1[4] = {{0,0,0,0},{0,0,0,0},{0,0,0,0},{0,0,0,0}};
        gemm64(hrow, kW1t, hi, row16, acc1);
        float h1[4][4];
        #pragma unroll
        for (int n = 0; n < 4; ++n) {
            const float bias = kb1[n * 16 + row16];
            #pragma unroll
            for (int r = 0; r < 4; ++r) {
                h1[n][r] = fmaxf(h0[n][r] + acc1[n][r] + bias, 0.f);
                H_s[wrow + hi * 4 + r][n * 16 + row16] = (__bf16)h1[n][r];
            }
        }
        __builtin_amdgcn_wave_barrier();

        f32x4 acc2[4] = {{0,0,0,0},{0,0,0,0},{0,0,0,0},{0,0,0,0}};
        gemm64(hrow, kW2t, hi, row16, acc2);

        // scores immediately (frees kk): head = 2n + (row16>>3)
        #pragma unroll
        for (int n = 0; n < 4; ++n) {
            const float bias = kb2[n * 16 + row16];
            const float qv   = q[n * 16 + row16];
            #pragma unroll
            for (int r = 0; r < 4; ++r) {
                const float kk = h1[n][r] + acc2[n][r] + bias;
                float p = qv * kk;
                p += __shfl_xor(p, 1);
                p += __shfl_xor(p, 2);
                p += __shfl_xor(p, 4);
                ex[n][r] = __expf(p * 0.35355339059327373f); // shift-free softmax: scores O(1)
            }
        }
    }

    // ================= V stack (af reused) =================
    float vv[4][4];
    {
        f32x4 acc[4] = {{0,0,0,0},{0,0,0,0},{0,0,0,0},{0,0,0,0}};
        #pragma unroll
        for (int kc = 0; kc < 5; ++kc) {
            #pragma unroll
            for (int n = 0; n < 4; ++n) {
                const bf16x8 bfr = *(const bf16x8*)(vW0t + (n * 16 + row16) * 168 + kc * 32 + hi * 8);
                acc[n] = __builtin_amdgcn_mfma_f32_16x16x32_bf16(af[kc], bfr, acc[n], 0, 0, 0);
            }
        }
        float h0[4][4];
        #pragma unroll
        for (int n = 0; n < 4; ++n) {
            const float bias = vb0[n * 16 + row16];
            #pragma unroll
            for (int r = 0; r < 4; ++r) {
                h0[n][r] = fmaxf(acc[n][r] + bias, 0.f);
                H_s[wrow + hi * 4 + r][n * 16 + row16] = (__bf16)h0[n][r];
            }
        }
        __builtin_amdgcn_wave_barrier();

        f32x4 acc1[4] = {{0,0,0,0},{0,0,0,0},{0,0,0,0},{0,0,0,0}};
        gemm64(hrow, vW1t, hi, row16, acc1);
        float h1[4][4];
        #pragma unroll
        for (int n = 0; n < 4; ++n) {
            const float bias = vb1[n * 16 + row16];
            #pragma unroll
            for (int r = 0; r < 4; ++r) {
                h1[n][r] = fmaxf(h0[n][r] + acc1[n][r] + bias, 0.f);
                H_s[wrow + hi * 4 + r][n * 16 + row16] = (__bf16)h1[n][r];
            }
        }
        __builtin_amdgcn_wave_barrier();

        f32x4 acc2[4] = {{0,0,0,0},{0,0,0,0},{0,0,0,0},{0,0,0,0}};
        gemm64(hrow, vW2t, hi, row16, acc2);
        #pragma unroll
        for (int n = 0; n < 4; ++n) {
            const float bias = vb2[n * 16 + row16];
            #pragma unroll
            for (int r = 0; r < 4; ++r)
                vv[n][r] = h1[n][r] + acc2[n][r] + bias;
        }
    }

    // ================= atomic scatter =================
    const int b3 = row16 >> 3;
    #pragma unroll
    for (int r = 0; r < 4; ++r) {
        const int drow = __shfl(dstn, hi * 4 + r);   // dst of edge e0 + hi*4 + r
        if ((lane & 7) == 0) {
            #pragma unroll
            for (int n = 0; n < 4; ++n)
                atomicAdd(&den[(size_t)drow * 8 + 2 * n + b3], ex[n][r]);
        }
        #pragma unroll
        for (int n = 0; n < 4; ++n)
            atomicAdd(&num[(size_t)drow * 64 + n * 16 + row16], ex[n][r] * vv[n][r]);
    }
}

// ---------------------------------------------------------------------------
// Node kernel: block = 64 nodes; aggr = relu(num/den) -> out stack -> skip.
// ---------------------------------------------------------------------------
__global__ __launch_bounds__(256) void node_kernel(
    const float* __restrict__ x,
    const float* __restrict__ num, const float* __restrict__ den,
    const float* __restrict__ ob0, const float* __restrict__ ob1, const float* __restrict__ ob2,
    const __bf16* __restrict__ oW0t, const __bf16* __restrict__ oW1t, const __bf16* __restrict__ oW2t,
    float* __restrict__ out)
{
    __shared__ __bf16 A_s[64][72];
    __shared__ __bf16 H_s[64][72];

    const int tid  = threadIdx.x;
    const int lane = tid & 63;
    const int w    = tid >> 6;
    const int n0   = blockIdx.x * 64;
    const int row16 = lane & 15;
    const int hi    = lane >> 4;

    for (int i = tid; i < 64 * 16; i += 256) {
        const int r = i >> 4, cc = (i & 15) * 4;
        const int node = n0 + r;
        bf16x4 h; h[0] = h[1] = h[2] = h[3] = (__bf16)0.f;
        if (node < N_NODES) {
            const float dh = den[(size_t)node * 8 + (cc >> 3)];
            if (dh > 0.f) {
                const float4 f = *(const float4*)&num[(size_t)node * 64 + cc];
                const float inv = 1.f / dh;
                h[0] = (__bf16)fmaxf(f.x * inv, 0.f);
                h[1] = (__bf16)fmaxf(f.y * inv, 0.f);
                h[2] = (__bf16)fmaxf(f.z * inv, 0.f);
                h[3] = (__bf16)fmaxf(f.w * inv, 0.f);
            }
        }
        *(bf16x4*)&A_s[r][cc] = h;
    }
    __syncthreads();

    const __bf16* arow = &A_s[w * 16 + row16][0];
    const __bf16* hrow = &H_s[w * 16 + row16][0];

    f32x4 acc[4] = {{0,0,0,0},{0,0,0,0},{0,0,0,0},{0,0,0,0}};
    gemm64(arow, oW0t, hi, row16, acc);
    float h0[4][4];
    #pragma unroll
    for (int n = 0; n < 4; ++n) {
        const float bias = ob0[n * 16 + row16];
        #pragma unroll
        for (int r = 0; r < 4; ++r) {
            h0[n][r] = fmaxf(acc[n][r] + bias, 0.f);
            H_s[w * 16 + hi * 4 + r][n * 16 + row16] = (__bf16)h0[n][r];
        }
    }
    __builtin_amdgcn_wave_barrier();

    f32x4 acc1[4] = {{0,0,0,0},{0,0,0,0},{0,0,0,0},{0,0,0,0}};
    gemm64(hrow, oW1t, hi, row16, acc1);
    float h1[4][4];
    #pragma unroll
    for (int n = 0; n < 4; ++n) {
        const float bias = ob1[n * 16 + row16];
        #pragma unroll
        for (int r = 0; r < 4; ++r) {
            h1[n][r] = fmaxf(h0[n][r] + acc1[n][r] + bias, 0.f);
            H_s[w * 16 + hi * 4 + r][n * 16 + row16] = (__bf16)h1[n][r];
        }
    }
    __builtin_amdgcn_wave_barrier();

    f32x4 acc2[4] = {{0,0,0,0},{0,0,0,0},{0,0,0,0},{0,0,0,0}};
    gemm64(hrow, oW2t, hi, row16, acc2);
    #pragma unroll
    for (int n = 0; n < 4; ++n) {
        const float bias = ob2[n * 16 + row16];
        #pragma unroll
        for (int r = 0; r < 4; ++r) {
            const int node = n0 + w * 16 + hi * 4 + r;
            if (node < N_NODES) {
                const int col = n * 16 + row16;
                const float o = h1[n][r] + acc2[n][r] + bias;
                out[(size_t)node * 64 + col] = fmaxf(x[(size_t)node * 64 + col] + o, 0.f);
            }
        }
    }
}

extern "C" void kernel_launch(void* const* d_in, const int* in_sizes, int n_in,
                              void* d_out, int out_size, void* d_ws, size_t ws_size,
                              hipStream_t stream) {
    const float* x  = (const float*)d_in[0];
    const float* ea = (const float*)d_in[1];
    const int*   ei = (const int*)d_in[2];
    const float* q  = (const float*)d_in[3];
    const float* kW0 = (const float*)d_in[4];  const float* kb0 = (const float*)d_in[5];
    const float* kW1 = (const float*)d_in[6];  const float* kb1 = (const float*)d_in[7];
    const float* kW2 = (const float*)d_in[8];  const float* kb2 = (const float*)d_in[9];
    const float* vW0 = (const float*)d_in[10]; const float* vb0 = (const float*)d_in[11];
    const float* vW1 = (const float*)d_in[12]; const float* vb1 = (const float*)d_in[13];
    const float* vW2 = (const float*)d_in[14]; const float* vb2 = (const float*)d_in[15];
    const float* oW0 = (const float*)d_in[16]; const float* ob0 = (const float*)d_in[17];
    const float* oW1 = (const float*)d_in[18]; const float* ob1 = (const float*)d_in[19];
    const float* oW2 = (const float*)d_in[20]; const float* ob2 = (const float*)d_in[21];

    char* ws = (char*)d_ws;
    float*  num  = (float*)(ws + WS_NUM_OFF);
    float*  den  = (float*)(ws + WS_DEN_OFF);
    __bf16* wts  = (__bf16*)(ws + WS_WTS_OFF);
    __bf16* kW0t = wts;
    __bf16* vW0t = wts + BIG_ELEMS;
    __bf16* sm   = wts + 2 * BIG_ELEMS;
    __bf16* kW1t = sm;                   __bf16* kW2t = sm + SMALL_ELEMS;
    __bf16* vW1t = sm + 2 * SMALL_ELEMS; __bf16* vW2t = sm + 3 * SMALL_ELEMS;
    __bf16* oW0t = sm + 4 * SMALL_ELEMS; __bf16* oW1t = sm + 5 * SMALL_ELEMS;
    __bf16* oW2t = sm + 6 * SMALL_ELEMS;

    hipMemsetAsync(d_ws, 0, (size_t)N_NODES * (64 + 8) * sizeof(float), stream);

    prep_kernel<<<210, 256, 0, stream>>>(kW0, kW1, kW2, vW0, vW1, vW2, oW0, oW1, oW2, wts);

    edge_kernel<<<E_EDGES / 64, 256, 0, stream>>>(
        x, ea, ei, q,
        kb0, kb1, kb2, vb0, vb1, vb2,
        kW0t, kW1t, kW2t, vW0t, vW1t, vW2t,
        num, den);

    node_kernel<<<(N_NODES + 63) / 64, 256, 0, stream>>>(
        x, num, den, ob0, ob1, ob2, oW0t, oW1t, oW2t, (float*)d_out);
}